// Round 5
// baseline (306.646 us; speedup 1.0000x reference)
//
#include <hip/hip_runtime.h>
#include <cstdint>
#include <cstddef>

// Problem constants
#define SS_ 256
#define LL_ 4
#define HH_ 1024

// ws layout
#define ZM_OFF   ((size_t)0)                        // uint32 [2][64][4][2][8] = 8192 zero-row bitmasks
#define PA_OFF   ((size_t)8192)                     // float [shalf2][t2][64][4][1024] = 1048576
#define DEN_OFF  ((size_t)(8192 + 1048576))         // float [shalf2][t2][64][4] = 1024
#define Y_REST   ((size_t)(8192 + 1048576 + 1024))

typedef const __attribute__((address_space(1))) void* gp1_t;
typedef __attribute__((address_space(3))) void* lp3_t;
#define GLDS16(g, l) __builtin_amdgcn_global_load_lds((gp1_t)(g), (lp3_t)(l), 16, 0, 0)

// ---------------------------------------------------------------------------
// Main fused kernel: layernorm + score + exp + online pooled accumulation.
// grid = 1024: idx = (t<<9) | (b<<3) | (l<<1) | shalf ; block = 512 (8 waves)
// Each wave owns 16 rows (s = r*8 + wid). Per-wave DOUBLE-BUFFERED LDS slots
// filled via global_load_lds DMA (no VGPR cost): row r+2 streams while row r
// computes. Counted s_waitcnt vmcnt(4) keeps exactly one row outstanding at
// every point -> latency fully hidden, BW-bound. Hot loop has NO stores
// (zero-flags -> per-wave bitmask stored once at end) so vmcnt is exact.
// One merged 3-value 6-level shfl chain per row: {sum x, sum x^2, sum x*p};
// dot via d = (s3 - m*sump)*rstd*rescale; mean-shift folded into scalar cm.
// MODE 0: normal pass (assumes mask==1, records zero-row bitmask).
// MODE 1: fixup; rebuilds first-zero index from bitmasks, early-exit if the
//         mask is all-ones for this (t,b) (true for this data).
// ---------------------------------------------------------------------------
template <int MODE>
__global__ __launch_bounds__(512) void attn_pool(const float* __restrict__ A_,
                                                 const float* __restrict__ B_,
                                                 const float* __restrict__ P_,
                                                 float* __restrict__ ws) {
  __shared__ float lds[16384];   // 8 waves x 2 slots x 1024 floats (64 KB); reused for combine
  __shared__ int wmin[8];

  int idx = blockIdx.x;
  int shalf = idx & 1;
  int l = (idx >> 1) & 3;
  int bb = (idx >> 3) & 63;
  int t = idx >> 9;
  int tid = threadIdx.x;
  int wid = tid >> 6;
  int ln = tid & 63;

  uint32_t* zmws = reinterpret_cast<uint32_t*>(ws) + ZM_OFF;

  int fz = SS_;
  if (MODE == 1) {
    int myfz = SS_;
    if (tid < SS_) {
      int sh_s = tid >> 7, sl_s = tid & 127;
      int wid_s = sl_s & 7, r_s = sl_s >> 3;
      const uint32_t* zb = zmws + ((size_t)(t * 64 + bb) * 4) * 16 + sh_s * 8 + wid_s;
      uint32_t all4 = (zb[0 * 16] >> r_s) & (zb[1 * 16] >> r_s) &
                      (zb[2 * 16] >> r_s) & (zb[3 * 16] >> r_s) & 1u;
      myfz = all4 ? tid : SS_;
    }
#pragma unroll
    for (int off = 32; off > 0; off >>= 1) myfz = min(myfz, __shfl_xor(myfz, off));
    if (ln == 0) wmin[wid] = myfz;
    __syncthreads();
#pragma unroll
    for (int w = 0; w < 8; ++w) fz = min(fz, wmin[w]);
    if (fz >= SS_) return;  // mask all-ones: keep pass-0 result
    __syncthreads();
  }

  const float* __restrict__ X = t ? B_ : A_;

  // p[b,l,:] in registers, same lane mapping as row loads
  float pv[16];
  {
    const float4* pr = reinterpret_cast<const float4*>(P_ + ((size_t)bb * LL_ + l) * HH_);
#pragma unroll
    for (int k = 0; k < 4; ++k) {
      float4 v = pr[k * 64 + ln];
      pv[4 * k + 0] = v.x; pv[4 * k + 1] = v.y;
      pv[4 * k + 2] = v.z; pv[4 * k + 3] = v.w;
    }
  }
  float sump = 0.f;
  {
#pragma unroll
    for (int j = 0; j < 16; ++j) sump += pv[j];
#pragma unroll
    for (int off = 32; off > 0; off >>= 1) sump += __shfl_xor(sump, off);
  }

  const float* base = X + (((size_t)bb * SS_ + (size_t)shalf * 128) * LL_ + l) * HH_;
  float* slot0 = lds + wid * 2048;
  float* slot1 = slot0 + 1024;

  float acc[16];
#pragma unroll
  for (int j = 0; j < 16; ++j) acc[j] = 0.f;
  float den = 0.f, cm = 0.f;
  uint32_t zm = 0;

  // all prologue vmem (p loads) consumed; make vmcnt exact before staging
  asm volatile("s_waitcnt vmcnt(0)" ::: "memory");
  {
    const float* rb0 = base + (size_t)(0 * 8 + wid) * 4096;
    GLDS16(rb0 + ln * 4, slot0);
    GLDS16(rb0 + 256 + ln * 4, slot0 + 256);
    GLDS16(rb0 + 512 + ln * 4, slot0 + 512);
    GLDS16(rb0 + 768 + ln * 4, slot0 + 768);
    const float* rb1 = base + (size_t)(1 * 8 + wid) * 4096;
    GLDS16(rb1 + ln * 4, slot1);
    GLDS16(rb1 + 256 + ln * 4, slot1 + 256);
    GLDS16(rb1 + 512 + ln * 4, slot1 + 512);
    GLDS16(rb1 + 768 + ln * 4, slot1 + 768);
  }

#pragma unroll
  for (int r = 0; r < 16; ++r) {
    // row r staged (4 ops); row r+1's 4 may still be outstanding
    if (r < 15) { asm volatile("s_waitcnt vmcnt(4)" ::: "memory"); }
    else        { asm volatile("s_waitcnt vmcnt(0)" ::: "memory"); }
    __builtin_amdgcn_sched_barrier(0);

    float* sp = (r & 1) ? slot1 : slot0;
    const float4* spv = reinterpret_cast<const float4*>(sp);
    float4 v0 = spv[ln], v1 = spv[64 + ln], v2 = spv[128 + ln], v3 = spv[192 + ln];
    // make sure our ds_reads completed before DMA may overwrite this slot
    asm volatile("s_waitcnt lgkmcnt(0)" ::: "memory");
    __builtin_amdgcn_sched_barrier(0);
    if (r < 14) {
      const float* rb = base + (size_t)((r + 2) * 8 + wid) * 4096;
      GLDS16(rb + ln * 4, sp);
      GLDS16(rb + 256 + ln * 4, sp + 256);
      GLDS16(rb + 512 + ln * 4, sp + 512);
      GLDS16(rb + 768 + ln * 4, sp + 768);
    }

    float x[16] = {v0.x, v0.y, v0.z, v0.w, v1.x, v1.y, v1.z, v1.w,
                   v2.x, v2.y, v2.z, v2.w, v3.x, v3.y, v3.z, v3.w};
    float s1 = 0.f, s2 = 0.f, s3 = 0.f;
#pragma unroll
    for (int j = 0; j < 16; ++j) {
      s1 += x[j];
      s2 = fmaf(x[j], x[j], s2);
      s3 = fmaf(x[j], pv[j], s3);
    }
#pragma unroll
    for (int off = 32; off > 0; off >>= 1) {
      s1 += __shfl_xor(s1, off);
      s2 += __shfl_xor(s2, off);
      s3 += __shfl_xor(s3, off);
    }
    float m_ = s1 * (1.f / 1024.f);
    float var_ = fmaf(-m_, m_, s2 * (1.f / 1024.f));
    float rstd_ = rsqrtf(var_ + 1e-5f);
    float d_ = (s3 - m_ * sump) * rstd_ * 0.03125f;
    float e_ = __expf(d_);
    if (MODE == 0) {
      zm |= (s2 == 0.f) ? (1u << r) : 0u;
    } else {
      int sl = r * 8 + wid;
      if (shalf * 128 + sl >= fz) e_ = 0.f;
    }
    float coef_ = e_ * rstd_;
#pragma unroll
    for (int j = 0; j < 16; ++j) acc[j] = fmaf(coef_, x[j], acc[j]);
    cm = fmaf(coef_, m_, cm);
    den += e_;
  }

  if (MODE == 0) {
    if (ln == 0)
      zmws[(((size_t)t * 64 + bb) * 4 + l) * 16 + shalf * 8 + wid] = zm;
  }

  // fold the mean-shift correction: pa_j = sum coef*x_j - sum coef*m
#pragma unroll
  for (int j = 0; j < 16; ++j) acc[j] -= cm;

  // combine 8 wave-partials via LDS (reuse the staging buffer after barrier)
  __syncthreads();
#pragma unroll
  for (int k = 0; k < 4; ++k) {
#pragma unroll
    for (int j = 0; j < 4; ++j) lds[wid * 1024 + (k * 64 + ln) * 4 + j] = acc[4 * k + j];
  }
  __syncthreads();
  float* pa = ws + PA_OFF + ((((size_t)shalf * 2 + t) * 64 + bb) * 4 + l) * HH_;
  for (int e2 = tid; e2 < 1024; e2 += 512) {
    float tot = 0.f;
#pragma unroll
    for (int w = 0; w < 8; ++w) tot += lds[w * 1024 + e2];
    pa[e2] = tot;
  }
  __syncthreads();
  if (ln == 0) lds[wid] = den;
  __syncthreads();
  if (tid == 0) {
    float dd = 0.f;
#pragma unroll
    for (int w = 0; w < 8; ++w) dd += lds[w];
    ws[DEN_OFF + (((size_t)shalf * 2 + t) * 64 + bb) * 4 + l] = dd;
  }
}

// ---------------------------------------------------------------------------
// Merged head + out: per b, compute y[b, l*16+o] for all l, then BN+ReLU,
// tanh encodings and the final 66x3 matvec. grid = 64 (b), block = 256.
// ---------------------------------------------------------------------------
__global__ __launch_bounds__(256) void headout_kernel(
    const float* __restrict__ p, const float* __restrict__ fw, const float* __restrict__ fb,
    const float* __restrict__ ap, const float* __restrict__ bp,
    const float* __restrict__ gam, const float* __restrict__ bet,
    const float* __restrict__ rm, const float* __restrict__ rv,
    const float* __restrict__ msw, const float* __restrict__ msb,
    const float* __restrict__ dw, const float* __restrict__ db,
    const float* __restrict__ ws, float* __restrict__ out) {
  int bb = blockIdx.x;
  int t = threadIdx.x;
  __shared__ float red[256 * 17 + 16 * 17];
  __shared__ float yv[64];
  const float* den = ws + DEN_OFF;

  for (int l = 0; l < 4; ++l) {
    float inv_a = 1.0f / (den[((0 * 2 + 0) * 64 + bb) * 4 + l] +
                          den[((1 * 2 + 0) * 64 + bb) * 4 + l] + 1e-15f);
    float inv_b = 1.0f / (den[((0 * 2 + 1) * 64 + bb) * 4 + l] +
                          den[((1 * 2 + 1) * 64 + bb) * 4 + l] + 1e-15f);

    const float4* pa00 = reinterpret_cast<const float4*>(ws + PA_OFF + (((size_t)(0 * 2 + 0) * 64 + bb) * 4 + l) * HH_);
    const float4* pa10 = reinterpret_cast<const float4*>(ws + PA_OFF + (((size_t)(1 * 2 + 0) * 64 + bb) * 4 + l) * HH_);
    const float4* pb01 = reinterpret_cast<const float4*>(ws + PA_OFF + (((size_t)(0 * 2 + 1) * 64 + bb) * 4 + l) * HH_);
    const float4* pb11 = reinterpret_cast<const float4*>(ws + PA_OFF + (((size_t)(1 * 2 + 1) * 64 + bb) * 4 + l) * HH_);

    float4 pv = reinterpret_cast<const float4*>(p + ((size_t)bb * LL_ + l) * HH_)[t];
    float4 A0 = pa00[t], A1 = pa10[t], B0 = pb01[t], B1 = pb11[t];
    float av[4] = {(A0.x + A1.x) * inv_a, (A0.y + A1.y) * inv_a,
                   (A0.z + A1.z) * inv_a, (A0.w + A1.w) * inv_a};
    float bv[4] = {(B0.x + B1.x) * inv_b, (B0.y + B1.y) * inv_b,
                   (B0.z + B1.z) * inv_b, (B0.w + B1.w) * inv_b};
    float cp[4] = {pv.x, pv.y, pv.z, pv.w};

    float part[16];
#pragma unroll
    for (int o = 0; o < 16; ++o) part[o] = 0.f;

    const float* wl = fw + (size_t)l * 5120 * 16;
#pragma unroll
    for (int j = 0; j < 4; ++j) {
      int h = t * 4 + j;
      float c[5] = {cp[j], av[j], bv[j], cp[j] * av[j], cp[j] * bv[j]};
#pragma unroll
      for (int sec = 0; sec < 5; ++sec) {
        const float4* wr = reinterpret_cast<const float4*>(wl + ((size_t)sec * 1024 + h) * 16);
#pragma unroll
        for (int o4 = 0; o4 < 4; ++o4) {
          float4 w4 = wr[o4];
          part[o4 * 4 + 0] += c[sec] * w4.x;
          part[o4 * 4 + 1] += c[sec] * w4.y;
          part[o4 * 4 + 2] += c[sec] * w4.z;
          part[o4 * 4 + 3] += c[sec] * w4.w;
        }
      }
    }

#pragma unroll
    for (int o = 0; o < 16; ++o) red[t * 17 + o] = part[o];
    __syncthreads();
    {
      int o = t & 15, g = t >> 4;
      float sacc = 0.f;
#pragma unroll
      for (int i = 0; i < 16; ++i) sacc += red[(g * 16 + i) * 17 + o];
      red[256 * 17 + g * 17 + o] = sacc;
    }
    __syncthreads();
    if (t < 16) {
      float sacc = 0.f;
#pragma unroll
      for (int g = 0; g < 16; ++g) sacc += red[256 * 17 + g * 17 + t];
      yv[l * 16 + t] = sacc + fb[l * 16 + t];
    }
    __syncthreads();
  }

  if (t < 64) {
    int k = t;
    float y = yv[k];
    y = (y - rm[k]) * rsqrtf(rv[k] + 1e-5f) * gam[k] + bet[k];
    y = fmaxf(y, 0.f);
    float w0 = dw[0], b0 = db[0];
    float ape = tanhf(ap[bb] * w0 + b0);
    float bpe = tanhf(bp[bb] * w0 + b0);
#pragma unroll
    for (int c = 0; c < 3; ++c) {
      float v = y * msw[k * 3 + c];
#pragma unroll
      for (int off = 32; off > 0; off >>= 1) v += __shfl_xor(v, off);
      if (k == 0) out[bb * 3 + c] = v + ape * msw[64 * 3 + c] + bpe * msw[65 * 3 + c] + msb[c];
    }
  }
}

extern "C" void kernel_launch(void* const* d_in, const int* in_sizes, int n_in,
                              void* d_out, int out_size, void* d_ws, size_t ws_size,
                              hipStream_t stream) {
  (void)in_sizes; (void)n_in; (void)out_size; (void)ws_size;
  const float* a = (const float*)d_in[0];
  const float* b = (const float*)d_in[1];
  const float* p = (const float*)d_in[2];
  const float* ap = (const float*)d_in[3];
  const float* bp = (const float*)d_in[4];
  const float* ffnn_w = (const float*)d_in[5];
  const float* ffnn_b = (const float*)d_in[6];
  const float* bn_g = (const float*)d_in[7];
  const float* bn_b = (const float*)d_in[8];
  const float* bn_rm = (const float*)d_in[9];
  const float* bn_rv = (const float*)d_in[10];
  const float* ms_w = (const float*)d_in[11];
  const float* ms_b = (const float*)d_in[12];
  const float* dist_w = (const float*)d_in[13];
  const float* dist_b = (const float*)d_in[14];
  float* ws = (float*)d_ws;
  float* out = (float*)d_out;

  hipLaunchKernelGGL((attn_pool<0>), dim3(1024), dim3(512), 0, stream, a, b, p, ws);
  hipLaunchKernelGGL((attn_pool<1>), dim3(1024), dim3(512), 0, stream, a, b, p, ws);
  hipLaunchKernelGGL(headout_kernel, dim3(64), dim3(256), 0, stream,
                     p, ffnn_w, ffnn_b, ap, bp, bn_g, bn_b, bn_rm, bn_rv,
                     ms_w, ms_b, dist_w, dist_b, ws, out);
}

// Round 6
// 153.427 us; speedup vs baseline: 1.9986x; 1.9986x over previous
//
#include <hip/hip_runtime.h>
#include <cstdint>
#include <cstddef>

// Problem constants
#define SS_ 256
#define LL_ 4
#define HH_ 1024

// ws layout (in floats)
#define ZM_OFF   ((size_t)0)                          // uint32 [2][64][4][8] = 4096 u32 = 4096 floats
#define PA_OFF   ((size_t)4096)                       // float [q4][t2][64][4][1024] = 2097152
#define DEN_OFF  ((size_t)(4096 + 2097152))           // float [q4][t2][64][4] = 2048

// ---------------------------------------------------------------------------
// Main fused kernel: layernorm + score + exp + online pooled accumulation.
// grid = 512: idx = (t<<8) | (bb<<2) | q ; block = 512 (8 waves).
// KEY CHANGE vs round 4: each block owns (t, b, s-quarter) and ALL 4 layers.
// Wave w handles layer l = w&3, s-parity soff = w>>2; at step r the 8 waves
// together read s_local in {2r, 2r+1} x l in {0..3} = a CONTIGUOUS 32 KB
// chunk; each block streams a contiguous 1 MB range. This turns the chip-wide
// access pattern from 4KB-read/12KB-skip strides (which capped delivered BW
// at ~3.2 TB/s) into pure linear streams (m13-style, ~6.3 TB/s capable).
// Hot loop is round 4's proven 36-VGPR shape: single row buffer, p in regs,
// one merged 3-value 6-level shfl chain per row, mean-shift folded into cm.
// MODE 0: normal pass (assumes mask==1, records zero-row bitmasks).
// MODE 1: fixup; rebuilds first-zero index from bitmasks, early-exit if the
//         mask is all-ones for this (t,b) (true for this data).
// ---------------------------------------------------------------------------
template <int MODE>
__global__ __launch_bounds__(512) void attn_pool(const float* __restrict__ A_,
                                                 const float* __restrict__ B_,
                                                 const float* __restrict__ P_,
                                                 float* __restrict__ ws) {
  __shared__ float lds[8 * 1024];   // 32 KB combine buffer
  __shared__ float dshare[8];
  __shared__ int wmin[8];

  int idx = blockIdx.x;
  int q = idx & 3;
  int bb = (idx >> 2) & 63;
  int t = idx >> 8;
  int tid = threadIdx.x;
  int wid = tid >> 6;
  int ln = tid & 63;
  int l = wid & 3;      // this wave's layer
  int soff = wid >> 2;  // this wave's s parity (0/1)

  uint32_t* zmws = reinterpret_cast<uint32_t*>(ws);

  int fz = SS_;
  if (MODE == 1) {
    int myfz = SS_;
    if (tid < SS_) {
      int q_s = tid >> 6, sl_s = tid & 63;
      int w_s = (sl_s & 1) * 4, r_s = sl_s >> 1;
      const uint32_t* zb = zmws + (((size_t)t * 64 + bb) * 4 + q_s) * 8 + w_s;
      uint32_t all4 = ((zb[0] & zb[1] & zb[2] & zb[3]) >> r_s) & 1u;
      myfz = all4 ? tid : SS_;
    }
#pragma unroll
    for (int off = 32; off > 0; off >>= 1) myfz = min(myfz, __shfl_xor(myfz, off));
    if (ln == 0) wmin[wid] = myfz;
    __syncthreads();
#pragma unroll
    for (int w = 0; w < 8; ++w) fz = min(fz, wmin[w]);
    if (fz >= SS_) return;  // mask all-ones: keep pass-0 result
  }

  const float* __restrict__ X = t ? B_ : A_;

  // p[b,l,:] in registers (this wave's layer), same lane mapping as row loads
  float pv[16];
  {
    const float4* pr = reinterpret_cast<const float4*>(P_ + ((size_t)bb * LL_ + l) * HH_);
#pragma unroll
    for (int k = 0; k < 4; ++k) {
      float4 v = pr[k * 64 + ln];
      pv[4 * k + 0] = v.x; pv[4 * k + 1] = v.y;
      pv[4 * k + 2] = v.z; pv[4 * k + 3] = v.w;
    }
  }
  float sump = 0.f;
  {
#pragma unroll
    for (int j = 0; j < 16; ++j) sump += pv[j];
#pragma unroll
    for (int off = 32; off > 0; off >>= 1) sump += __shfl_xor(sump, off);
  }

  // block base: (b, s = q*64), wave base adds (soff*4 + l) rows of 1024
  const float* wbase = X + ((size_t)bb * SS_ + (size_t)q * 64) * (LL_ * HH_)
                         + (size_t)(soff * 4 + l) * HH_;

  float acc[16];
#pragma unroll
  for (int j = 0; j < 16; ++j) acc[j] = 0.f;
  float den = 0.f, cm = 0.f;
  uint32_t zm = 0;

  for (int r = 0; r < 32; ++r) {
    const float4* rp = reinterpret_cast<const float4*>(wbase + (size_t)r * (2 * LL_ * HH_));
    float x[16];
    {
      float4 v0 = rp[ln], v1 = rp[64 + ln], v2 = rp[128 + ln], v3 = rp[192 + ln];
      x[0] = v0.x;  x[1] = v0.y;  x[2] = v0.z;  x[3] = v0.w;
      x[4] = v1.x;  x[5] = v1.y;  x[6] = v1.z;  x[7] = v1.w;
      x[8] = v2.x;  x[9] = v2.y;  x[10] = v2.z; x[11] = v2.w;
      x[12] = v3.x; x[13] = v3.y; x[14] = v3.z; x[15] = v3.w;
    }
    float s1 = 0.f, s2 = 0.f, s3 = 0.f;
#pragma unroll
    for (int j = 0; j < 16; ++j) {
      s1 += x[j];
      s2 = fmaf(x[j], x[j], s2);
      s3 = fmaf(x[j], pv[j], s3);
    }
    // one merged 6-level chain for {s1,s2,s3}
#pragma unroll
    for (int off = 32; off > 0; off >>= 1) {
      s1 += __shfl_xor(s1, off);
      s2 += __shfl_xor(s2, off);
      s3 += __shfl_xor(s3, off);
    }
    float m_ = s1 * (1.f / 1024.f);
    float var_ = fmaf(-m_, m_, s2 * (1.f / 1024.f));
    float rstd_ = rsqrtf(var_ + 1e-5f);
    float d_ = (s3 - m_ * sump) * rstd_ * 0.03125f;
    float e_ = __expf(d_);
    if (MODE == 0) {
      zm |= (s2 == 0.f) ? (1u << r) : 0u;
    } else {
      int sg = q * 64 + 2 * r + soff;
      if (sg >= fz) e_ = 0.f;
    }
    float coef_ = e_ * rstd_;
#pragma unroll
    for (int j = 0; j < 16; ++j) acc[j] = fmaf(coef_, x[j], acc[j]);
    cm = fmaf(coef_, m_, cm);
    den += e_;
  }

  if (MODE == 0) {
    if (ln == 0)
      zmws[(((size_t)t * 64 + bb) * 4 + q) * 8 + wid] = zm;
  }

  // fold the mean-shift correction: pa_j = sum coef*x_j - sum coef*m
#pragma unroll
  for (int j = 0; j < 16; ++j) acc[j] -= cm;

  // combine: wave w and w+4 hold the two s-parity partials for layer l
#pragma unroll
  for (int k = 0; k < 4; ++k) {
#pragma unroll
    for (int j = 0; j < 4; ++j) lds[wid * 1024 + (k * 64 + ln) * 4 + j] = acc[4 * k + j];
  }
  if (ln == 0) dshare[wid] = den;
  __syncthreads();
  float* paq = ws + PA_OFF + (((size_t)q * 2 + t) * 64 + bb) * (4 * HH_);
  for (int e2 = tid; e2 < 4096; e2 += 512) {
    int lc = e2 >> 10, h = e2 & 1023;
    paq[(size_t)lc * HH_ + h] = lds[lc * 1024 + h] + lds[(lc + 4) * 1024 + h];
  }
  if (tid < 4) {
    ws[DEN_OFF + (((size_t)q * 2 + t) * 64 + bb) * 4 + tid] = dshare[tid] + dshare[tid + 4];
  }
}

// ---------------------------------------------------------------------------
// Merged head + out: per b, sum the 4 quarter-partials, normalize, compute
// y[b, l*16+o] for all l, then BN+ReLU, tanh encodings, final 66x3 matvec.
// grid = 64 (b), block = 256.
// ---------------------------------------------------------------------------
__global__ __launch_bounds__(256) void headout_kernel(
    const float* __restrict__ p, const float* __restrict__ fw, const float* __restrict__ fb,
    const float* __restrict__ ap, const float* __restrict__ bp,
    const float* __restrict__ gam, const float* __restrict__ bet,
    const float* __restrict__ rm, const float* __restrict__ rv,
    const float* __restrict__ msw, const float* __restrict__ msb,
    const float* __restrict__ dw, const float* __restrict__ db,
    const float* __restrict__ ws, float* __restrict__ out) {
  int bb = blockIdx.x;
  int t = threadIdx.x;
  __shared__ float red[256 * 17 + 16 * 17];
  __shared__ float yv[64];
  const float* den = ws + DEN_OFF;

  for (int l = 0; l < 4; ++l) {
    float sden_a = 1e-15f, sden_b = 1e-15f;
#pragma unroll
    for (int qq = 0; qq < 4; ++qq) {
      sden_a += den[(((size_t)qq * 2 + 0) * 64 + bb) * 4 + l];
      sden_b += den[(((size_t)qq * 2 + 1) * 64 + bb) * 4 + l];
    }
    float inv_a = 1.0f / sden_a;
    float inv_b = 1.0f / sden_b;

    float4 A = make_float4(0.f, 0.f, 0.f, 0.f), B = make_float4(0.f, 0.f, 0.f, 0.f);
#pragma unroll
    for (int qq = 0; qq < 4; ++qq) {
      const float4* pa_ = reinterpret_cast<const float4*>(
          ws + PA_OFF + ((((size_t)qq * 2 + 0) * 64 + bb) * 4 + l) * HH_);
      const float4* pb_ = reinterpret_cast<const float4*>(
          ws + PA_OFF + ((((size_t)qq * 2 + 1) * 64 + bb) * 4 + l) * HH_);
      float4 va = pa_[t], vb = pb_[t];
      A.x += va.x; A.y += va.y; A.z += va.z; A.w += va.w;
      B.x += vb.x; B.y += vb.y; B.z += vb.z; B.w += vb.w;
    }

    float4 pv = reinterpret_cast<const float4*>(p + ((size_t)bb * LL_ + l) * HH_)[t];
    float av[4] = {A.x * inv_a, A.y * inv_a, A.z * inv_a, A.w * inv_a};
    float bv[4] = {B.x * inv_b, B.y * inv_b, B.z * inv_b, B.w * inv_b};
    float cp[4] = {pv.x, pv.y, pv.z, pv.w};

    float part[16];
#pragma unroll
    for (int o = 0; o < 16; ++o) part[o] = 0.f;

    const float* wl = fw + (size_t)l * 5120 * 16;
#pragma unroll
    for (int j = 0; j < 4; ++j) {
      int h = t * 4 + j;
      float c[5] = {cp[j], av[j], bv[j], cp[j] * av[j], cp[j] * bv[j]};
#pragma unroll
      for (int sec = 0; sec < 5; ++sec) {
        const float4* wr = reinterpret_cast<const float4*>(wl + ((size_t)sec * 1024 + h) * 16);
#pragma unroll
        for (int o4 = 0; o4 < 4; ++o4) {
          float4 w4 = wr[o4];
          part[o4 * 4 + 0] += c[sec] * w4.x;
          part[o4 * 4 + 1] += c[sec] * w4.y;
          part[o4 * 4 + 2] += c[sec] * w4.z;
          part[o4 * 4 + 3] += c[sec] * w4.w;
        }
      }
    }

#pragma unroll
    for (int o = 0; o < 16; ++o) red[t * 17 + o] = part[o];
    __syncthreads();
    {
      int o = t & 15, g = t >> 4;
      float sacc = 0.f;
#pragma unroll
      for (int i = 0; i < 16; ++i) sacc += red[(g * 16 + i) * 17 + o];
      red[256 * 17 + g * 17 + o] = sacc;
    }
    __syncthreads();
    if (t < 16) {
      float sacc = 0.f;
#pragma unroll
      for (int g = 0; g < 16; ++g) sacc += red[256 * 17 + g * 17 + t];
      yv[l * 16 + t] = sacc + fb[l * 16 + t];
    }
    __syncthreads();
  }

  if (t < 64) {
    int k = t;
    float y = yv[k];
    y = (y - rm[k]) * rsqrtf(rv[k] + 1e-5f) * gam[k] + bet[k];
    y = fmaxf(y, 0.f);
    float w0 = dw[0], b0 = db[0];
    float ape = tanhf(ap[bb] * w0 + b0);
    float bpe = tanhf(bp[bb] * w0 + b0);
#pragma unroll
    for (int c = 0; c < 3; ++c) {
      float v = y * msw[k * 3 + c];
#pragma unroll
      for (int off = 32; off > 0; off >>= 1) v += __shfl_xor(v, off);
      if (k == 0) out[bb * 3 + c] = v + ape * msw[64 * 3 + c] + bpe * msw[65 * 3 + c] + msb[c];
    }
  }
}

extern "C" void kernel_launch(void* const* d_in, const int* in_sizes, int n_in,
                              void* d_out, int out_size, void* d_ws, size_t ws_size,
                              hipStream_t stream) {
  (void)in_sizes; (void)n_in; (void)out_size; (void)ws_size;
  const float* a = (const float*)d_in[0];
  const float* b = (const float*)d_in[1];
  const float* p = (const float*)d_in[2];
  const float* ap = (const float*)d_in[3];
  const float* bp = (const float*)d_in[4];
  const float* ffnn_w = (const float*)d_in[5];
  const float* ffnn_b = (const float*)d_in[6];
  const float* bn_g = (const float*)d_in[7];
  const float* bn_b = (const float*)d_in[8];
  const float* bn_rm = (const float*)d_in[9];
  const float* bn_rv = (const float*)d_in[10];
  const float* ms_w = (const float*)d_in[11];
  const float* ms_b = (const float*)d_in[12];
  const float* dist_w = (const float*)d_in[13];
  const float* dist_b = (const float*)d_in[14];
  float* ws = (float*)d_ws;
  float* out = (float*)d_out;

  hipLaunchKernelGGL((attn_pool<0>), dim3(512), dim3(512), 0, stream, a, b, p, ws);
  hipLaunchKernelGGL((attn_pool<1>), dim3(512), dim3(512), 0, stream, a, b, p, ws);
  hipLaunchKernelGGL(headout_kernel, dim3(64), dim3(256), 0, stream,
                     p, ffnn_w, ffnn_b, ap, bp, bn_g, bn_b, bn_rm, bn_rv,
                     ms_w, ms_b, dist_w, dist_b, ws, out);
}